// Round 1
// baseline (173.696 us; speedup 1.0000x reference)
//
#include <hip/hip_runtime.h>
#include <hip/hip_bf16.h>

#define N_NODES 10000
#define N_EDGES 160000
#define DF 128
#define NH 4
#define HD 512   // NH * DF
#define MAX_DEG 1024

// ---------------- utility ----------------
__global__ void zero_int(int* p, int n) {
    int i = blockIdx.x * blockDim.x + threadIdx.x;
    if (i < n) p[i] = 0;
}

// ---------------- GEMM 1: h = feat @ W_fc  ([N,128] @ [128,512] -> [N,512]) ----------------
__global__ __launch_bounds__(256) void gemm_h(const float* __restrict__ feat,
                                              const float* __restrict__ Wfc,
                                              float* __restrict__ h) {
    __shared__ float As[64][132];   // 64 rows x 128 K (+pad)
    __shared__ float Bs[128][68];   // 128 K x 64 cols (+pad)
    int tid = threadIdx.x;
    int rowbase = blockIdx.y * 64;
    int colbase = blockIdx.x * 64;

    // load A tile (64 x 128), float4
    for (int i = tid; i < 64 * 32; i += 256) {
        int r = i >> 5, c4 = (i & 31) << 2;
        float4 v = make_float4(0.f, 0.f, 0.f, 0.f);
        int gr = rowbase + r;
        if (gr < N_NODES) v = *(const float4*)&feat[(size_t)gr * DF + c4];
        As[r][c4] = v.x; As[r][c4 + 1] = v.y; As[r][c4 + 2] = v.z; As[r][c4 + 3] = v.w;
    }
    // load B tile (128 x 64), float4
    for (int i = tid; i < 128 * 16; i += 256) {
        int r = i >> 4, c4 = (i & 15) << 2;
        float4 v = *(const float4*)&Wfc[(size_t)r * HD + colbase + c4];
        Bs[r][c4] = v.x; Bs[r][c4 + 1] = v.y; Bs[r][c4 + 2] = v.z; Bs[r][c4 + 3] = v.w;
    }
    __syncthreads();

    int tx = tid & 15, ty = tid >> 4;
    float acc[4][4] = {};
    for (int k = 0; k < 128; ++k) {
        float a[4], b[4];
#pragma unroll
        for (int i = 0; i < 4; i++) a[i] = As[ty * 4 + i][k];
#pragma unroll
        for (int j = 0; j < 4; j++) b[j] = Bs[k][tx * 4 + j];
#pragma unroll
        for (int i = 0; i < 4; i++)
#pragma unroll
            for (int j = 0; j < 4; j++) acc[i][j] += a[i] * b[j];
    }
#pragma unroll
    for (int i = 0; i < 4; i++) {
        int gr = rowbase + ty * 4 + i;
        if (gr >= N_NODES) break;
#pragma unroll
        for (int j = 0; j < 4; j++)
            h[(size_t)gr * HD + colbase + tx * 4 + j] = acc[i][j];
    }
}

// ---------------- e_ns / e_nd: per (node, head) dot(h, att) over 128 dims ----------------
__global__ __launch_bounds__(256) void calc_e(const float* __restrict__ h,
                                              const float* __restrict__ att_ns,
                                              const float* __restrict__ att_nd,
                                              float* __restrict__ e_ns,
                                              float* __restrict__ e_nd) {
    int gw = (blockIdx.x * blockDim.x + threadIdx.x) >> 6;  // global wave id
    int lane = threadIdx.x & 63;
    if (gw >= N_NODES * NH) return;
    int n = gw >> 2, hh = gw & 3;
    const float* hp = h + (size_t)n * HD + hh * DF;
    float v0 = hp[lane], v1 = hp[lane + 64];
    float s = v0 * att_ns[hh * DF + lane] + v1 * att_ns[hh * DF + lane + 64];
    float t = v0 * att_nd[hh * DF + lane] + v1 * att_nd[hh * DF + lane + 64];
#pragma unroll
    for (int off = 32; off > 0; off >>= 1) {
        s += __shfl_down(s, off);
        t += __shfl_down(t, off);
    }
    if (lane == 0) {
        e_ns[n * NH + hh] = s;
        e_nd[n * NH + hh] = t;
    }
}

// ---------------- CSR build ----------------
__global__ void count_deg(const int* __restrict__ dst, int* __restrict__ deg) {
    int e = blockIdx.x * blockDim.x + threadIdx.x;
    if (e < N_EDGES) atomicAdd(&deg[dst[e]], 1);
}

__global__ __launch_bounds__(1024) void scan_deg(const int* __restrict__ deg,
                                                 int* __restrict__ row_st,
                                                 int* __restrict__ cursor) {
    __shared__ int buf[1024];
    __shared__ int carry;
    int tid = threadIdx.x;
    if (tid == 0) carry = 0;
    __syncthreads();
    for (int base = 0; base < N_NODES; base += 1024) {
        int v = (base + tid < N_NODES) ? deg[base + tid] : 0;
        buf[tid] = v;
        __syncthreads();
        for (int off = 1; off < 1024; off <<= 1) {
            int add = (tid >= off) ? buf[tid - off] : 0;
            __syncthreads();
            buf[tid] += add;
            __syncthreads();
        }
        int total_prev = carry;
        int excl = total_prev + buf[tid] - v;
        if (base + tid < N_NODES) {
            row_st[base + tid] = excl;
            cursor[base + tid] = excl;
        }
        __syncthreads();
        if (tid == 0) carry = total_prev + buf[1023];
        __syncthreads();
    }
    if (tid == 0) row_st[N_NODES] = carry;
}

__global__ void scatter_edges(const int* __restrict__ dst, int* __restrict__ cursor,
                              int* __restrict__ edge_l) {
    int e = blockIdx.x * blockDim.x + threadIdx.x;
    if (e < N_EDGES) {
        int p = atomicAdd(&cursor[dst[e]], 1);
        edge_l[p] = e;
    }
}

// ---------------- softmax + weighted aggregate, one block per dst node ----------------
__global__ __launch_bounds__(256) void attn_agg(const float* __restrict__ h,
                                                const float* __restrict__ e_ns,
                                                const float* __restrict__ e_nd,
                                                const int* __restrict__ src,
                                                const int* __restrict__ row_st,
                                                const int* __restrict__ edge_l,
                                                float* __restrict__ agg) {
    __shared__ float sc[MAX_DEG][NH];
    __shared__ int ssrc[MAX_DEG];
    __shared__ float ssum[NH];
    int n = blockIdx.x;
    int tid = threadIdx.x;
    int beg = row_st[n], end = row_st[n + 1];
    int deg = end - beg;
    if (deg > MAX_DEG) deg = MAX_DEG;  // safety clamp (avg deg = 16; never hit)

    // scores with LeakyReLU(0.2)
    for (int i = tid; i < deg; i += 256) {
        int e = edge_l[beg + i];
        int s = src[e];
        ssrc[i] = s;
#pragma unroll
        for (int hh = 0; hh < NH; hh++) {
            float v = e_ns[s * NH + hh] + e_nd[n * NH + hh];
            sc[i][hh] = v > 0.f ? v : 0.2f * v;
        }
    }
    __syncthreads();
    // per-head max -> exp -> sum (deg is small; 4 threads serial)
    if (tid < NH) {
        float m = -1e30f;
        for (int i = 0; i < deg; i++) m = fmaxf(m, sc[i][tid]);
        float s = 0.f;
        for (int i = 0; i < deg; i++) {
            float ex = __expf(sc[i][tid] - m);
            sc[i][tid] = ex;
            s += ex;
        }
        ssum[tid] = s;
    }
    __syncthreads();

    // each thread owns components tid and tid+256 of the 512-wide output
    int c0 = tid, c1 = tid + 256;
    int h0 = c0 >> 7, h1 = c1 >> 7;
    float acc0 = 0.f, acc1 = 0.f;
    for (int i = 0; i < deg; i++) {
        const float* hp = h + (size_t)ssrc[i] * HD;
        float a0 = sc[i][h0], a1 = sc[i][h1];
        acc0 += a0 * hp[c0];
        acc1 += a1 * hp[c1];
    }
    float w0 = deg > 0 ? 1.f / ssum[h0] : 0.f;
    float w1 = deg > 0 ? 1.f / ssum[h1] : 0.f;
    agg[(size_t)n * HD + c0] = acc0 * w0;
    agg[(size_t)n * HD + c1] = acc1 * w1;
}

// ---------------- GEMM 2: out = agg @ W_trans + b  ([N,512] @ [512,128]) ----------------
__global__ __launch_bounds__(256) void gemm_out(const float* __restrict__ agg,
                                                const float* __restrict__ Wt,
                                                const float* __restrict__ bias,
                                                float* __restrict__ out) {
    __shared__ float As[64][132];
    __shared__ float Bs[128][68];
    int tid = threadIdx.x;
    int rowbase = blockIdx.y * 64;
    int colbase = blockIdx.x * 64;
    int tx = tid & 15, ty = tid >> 4;
    float acc[4][4] = {};

    for (int kb = 0; kb < HD; kb += 128) {
        __syncthreads();
        for (int i = tid; i < 64 * 32; i += 256) {
            int r = i >> 5, c4 = (i & 31) << 2;
            float4 v = make_float4(0.f, 0.f, 0.f, 0.f);
            int gr = rowbase + r;
            if (gr < N_NODES) v = *(const float4*)&agg[(size_t)gr * HD + kb + c4];
            As[r][c4] = v.x; As[r][c4 + 1] = v.y; As[r][c4 + 2] = v.z; As[r][c4 + 3] = v.w;
        }
        for (int i = tid; i < 128 * 16; i += 256) {
            int r = i >> 4, c4 = (i & 15) << 2;
            float4 v = *(const float4*)&Wt[(size_t)(kb + r) * DF + colbase + c4];
            Bs[r][c4] = v.x; Bs[r][c4 + 1] = v.y; Bs[r][c4 + 2] = v.z; Bs[r][c4 + 3] = v.w;
        }
        __syncthreads();
        for (int k = 0; k < 128; ++k) {
            float a[4], b[4];
#pragma unroll
            for (int i = 0; i < 4; i++) a[i] = As[ty * 4 + i][k];
#pragma unroll
            for (int j = 0; j < 4; j++) b[j] = Bs[k][tx * 4 + j];
#pragma unroll
            for (int i = 0; i < 4; i++)
#pragma unroll
                for (int j = 0; j < 4; j++) acc[i][j] += a[i] * b[j];
        }
    }
#pragma unroll
    for (int i = 0; i < 4; i++) {
        int gr = rowbase + ty * 4 + i;
        if (gr >= N_NODES) break;
#pragma unroll
        for (int j = 0; j < 4; j++)
            out[(size_t)gr * DF + colbase + tx * 4 + j] = acc[i][j] + bias[colbase + tx * 4 + j];
    }
}

extern "C" void kernel_launch(void* const* d_in, const int* in_sizes, int n_in,
                              void* d_out, int out_size, void* d_ws, size_t ws_size,
                              hipStream_t stream) {
    const float* feat   = (const float*)d_in[0];
    const float* W_fc   = (const float*)d_in[1];
    const float* att_ns = (const float*)d_in[2];
    const float* att_nd = (const float*)d_in[3];
    const float* W_tr   = (const float*)d_in[4];
    const float* b_tr   = (const float*)d_in[5];
    const int*   src    = (const int*)d_in[6];
    const int*   dst    = (const int*)d_in[7];
    float* out = (float*)d_out;

    char* ws = (char*)d_ws;
    float* h    = (float*)(ws + 0);           // 10000*512*4 = 20,480,000
    float* agg  = (float*)(ws + 20480000);    // 20,480,000
    float* e_ns = (float*)(ws + 40960000);    // 160,000
    float* e_nd = (float*)(ws + 41120000);    // 160,000
    int* deg    = (int*)(ws + 41280000);      // 40,000
    int* row_st = (int*)(ws + 41320064);      // 40,004 (+pad)
    int* cursor = (int*)(ws + 41360192);      // 40,000
    int* edge_l = (int*)(ws + 41400256);      // 640,000  -> total ~42.1 MB

    zero_int<<<(N_NODES + 255) / 256, 256, 0, stream>>>(deg, N_NODES);
    gemm_h<<<dim3(HD / 64, (N_NODES + 63) / 64), 256, 0, stream>>>(feat, W_fc, h);
    calc_e<<<(N_NODES * NH * 64) / 256, 256, 0, stream>>>(h, att_ns, att_nd, e_ns, e_nd);
    count_deg<<<(N_EDGES + 255) / 256, 256, 0, stream>>>(dst, deg);
    scan_deg<<<1, 1024, 0, stream>>>(deg, row_st, cursor);
    scatter_edges<<<(N_EDGES + 255) / 256, 256, 0, stream>>>(dst, cursor, edge_l);
    attn_agg<<<N_NODES, 256, 0, stream>>>(h, e_ns, e_nd, src, row_st, edge_l, agg);
    gemm_out<<<dim3(DF / 64, (N_NODES + 63) / 64), 256, 0, stream>>>(agg, W_tr, b_tr, out);
}

// Round 2
// 90.278 us; speedup vs baseline: 1.9240x; 1.9240x over previous
//
#include <hip/hip_runtime.h>
#include <hip/hip_bf16.h>

#define N_NODES 10000
#define N_EDGES 160000
#define DF 128
#define NH 4
#define HD 512   // NH * DF
#define MAXD 256

typedef __attribute__((ext_vector_type(8))) short short8;
typedef __attribute__((ext_vector_type(4))) float f32x4;

__device__ __forceinline__ ushort f2b(float x) {
    union { __hip_bfloat16 b; ushort u; } cv;
    cv.b = __float2bfloat16(x);
    return cv.u;
}
__device__ __forceinline__ float b2f(ushort u) {
    union { ushort u; __hip_bfloat16 b; } cv;
    cv.u = u;
    return __bfloat162float(cv.b);
}

// ---------------- prep: convert feat->bf16, transpose+convert weights, zero deg ----------------
__global__ __launch_bounds__(256) void prep(const float* __restrict__ feat,
                                            const float* __restrict__ Wfc,
                                            const float* __restrict__ Wt,
                                            ushort* __restrict__ featb,
                                            ushort* __restrict__ Wfct,
                                            ushort* __restrict__ Wtt,
                                            int* __restrict__ deg) {
    int t = blockIdx.x * 256 + threadIdx.x;
    if (t < 320000) {  // feat: 1,280,000 f32 -> bf16, 4 per thread
        float4 v = ((const float4*)feat)[t];
        ushort4 o;
        o.x = f2b(v.x); o.y = f2b(v.y); o.z = f2b(v.z); o.w = f2b(v.w);
        ((ushort4*)featb)[t] = o;
        return;
    }
    t -= 320000;
    if (t < 65536) {  // Wfct[c][k] = Wfc[k][c],  [128,512] -> [512,128]
        int k = t & 127, c = t >> 7;
        Wfct[c * 128 + k] = f2b(Wfc[k * 512 + c]);
        return;
    }
    t -= 65536;
    if (t < 65536) {  // Wtt[c][k] = Wt[k][c],  [512,128] -> [128,512]
        int k = t & 511, c = t >> 9;
        Wtt[c * 512 + k] = f2b(Wt[k * 128 + c]);
        return;
    }
    t -= 65536;
    if (t < N_NODES) deg[t] = 0;
}

// ---------------- CSR build ----------------
__global__ void count_deg(const int* __restrict__ dst, int* __restrict__ deg) {
    int e = blockIdx.x * blockDim.x + threadIdx.x;
    if (e < N_EDGES) atomicAdd(&deg[dst[e]], 1);
}

__global__ __launch_bounds__(1024) void scan_deg(const int* __restrict__ deg,
                                                 int* __restrict__ row_st,
                                                 int* __restrict__ cursor) {
    __shared__ int wsum[16];
    int t = threadIdx.x;
    int local[10];
    int s = 0;
    if (t < 1000) {
#pragma unroll
        for (int i = 0; i < 10; ++i) { local[i] = deg[t * 10 + i]; s += local[i]; }
    }
    int incl = s;
#pragma unroll
    for (int off = 1; off < 64; off <<= 1) {
        int v = __shfl_up(incl, off);
        if ((t & 63) >= off) incl += v;
    }
    if ((t & 63) == 63) wsum[t >> 6] = incl;
    __syncthreads();
    if (t < 16) {
        int v = wsum[t];
        int inc2 = v;
#pragma unroll
        for (int off = 1; off < 16; off <<= 1) {
            int x = __shfl_up(inc2, off);
            if (t >= off) inc2 += x;
        }
        wsum[t] = inc2 - v;  // exclusive wave offset
    }
    __syncthreads();
    if (t < 1000) {
        int run = wsum[t >> 6] + incl - s;
#pragma unroll
        for (int i = 0; i < 10; ++i) {
            row_st[t * 10 + i] = run;
            cursor[t * 10 + i] = run;
            run += local[i];
        }
        if (t == 999) row_st[N_NODES] = run;
    }
}

__global__ void scatter_edges(const int* __restrict__ dst, int* __restrict__ cursor,
                              int* __restrict__ edge_l) {
    int e = blockIdx.x * blockDim.x + threadIdx.x;
    if (e < N_EDGES) {
        int p = atomicAdd(&cursor[dst[e]], 1);
        edge_l[p] = e;
    }
}

// ---------------- bf16 MFMA GEMM:  C[M,NTOT] = A[M,KTOT] @ B, B given as Bt[NTOT,KTOT] ----------------
// 64x64 block tile, 4 waves in 2x2, each wave 32x32 via 2x2 mfma_16x16x32 frags.
// LDS layout: 64 rows x 16 chunks of 8 bf16; chunk slot = chunk ^ (row&7)  (T2 swizzle)
__device__ __forceinline__ void stage_tile(const ushort* __restrict__ G, int g_rowbase,
                                           int rows_total, int g_ld, int g_colbase,
                                           ushort* __restrict__ S) {
    int t = threadIdx.x;
    for (int idx = t; idx < 64 * 16; idx += 256) {
        int r = idx >> 4, c = idx & 15;
        uint4 v = make_uint4(0, 0, 0, 0);
        int gr = g_rowbase + r;
        if (gr < rows_total) v = *(const uint4*)&G[(size_t)gr * g_ld + g_colbase + c * 8];
        *(uint4*)&S[(size_t)(r * 16 + (c ^ (r & 7))) * 8] = v;
    }
}

__device__ __forceinline__ short8 lds_frag(const ushort* __restrict__ S, int row, int chunk) {
    return *(const short8*)&S[(size_t)(row * 16 + (chunk ^ (row & 7))) * 8];
}

template <int KTOT, int NTOT, int MODE>  // MODE 0: bf16 out; MODE 1: f32 out + bias
__global__ __launch_bounds__(256) void gemm_bf16(const ushort* __restrict__ A,
                                                 const ushort* __restrict__ Bt,
                                                 const float* __restrict__ bias,
                                                 ushort* __restrict__ outb,
                                                 float* __restrict__ outf) {
    __shared__ ushort As[64 * 128];
    __shared__ ushort Bs[64 * 128];
    int rowbase = blockIdx.y * 64;
    int colbase = blockIdx.x * 64;
    int t = threadIdx.x, lane = t & 63, w = t >> 6;
    int wr = (w >> 1) * 32, wc = (w & 1) * 32;
    int lr = lane & 15, hi = lane >> 4;
    f32x4 acc[2][2] = {};
    for (int kb = 0; kb < KTOT; kb += 128) {
        stage_tile(A, rowbase, N_NODES, KTOT, kb, As);
        stage_tile(Bt, colbase, NTOT, KTOT, kb, Bs);
        __syncthreads();
#pragma unroll
        for (int kk = 0; kk < 4; ++kk) {
            int cc = kk * 4 + hi;
            short8 a0 = lds_frag(As, wr + lr, cc);
            short8 a1 = lds_frag(As, wr + 16 + lr, cc);
            short8 b0 = lds_frag(Bs, wc + lr, cc);
            short8 b1 = lds_frag(Bs, wc + 16 + lr, cc);
            acc[0][0] = __builtin_amdgcn_mfma_f32_16x16x32_bf16(a0, b0, acc[0][0], 0, 0, 0);
            acc[0][1] = __builtin_amdgcn_mfma_f32_16x16x32_bf16(a0, b1, acc[0][1], 0, 0, 0);
            acc[1][0] = __builtin_amdgcn_mfma_f32_16x16x32_bf16(a1, b0, acc[1][0], 0, 0, 0);
            acc[1][1] = __builtin_amdgcn_mfma_f32_16x16x32_bf16(a1, b1, acc[1][1], 0, 0, 0);
        }
        __syncthreads();
    }
#pragma unroll
    for (int i = 0; i < 2; ++i) {
#pragma unroll
        for (int reg = 0; reg < 4; ++reg) {
            int gr = rowbase + wr + i * 16 + hi * 4 + reg;
            if (gr >= N_NODES) continue;
#pragma unroll
            for (int j = 0; j < 2; ++j) {
                int gc = colbase + wc + j * 16 + lr;
                float v = acc[i][j][reg];
                if (MODE == 0) outb[(size_t)gr * NTOT + gc] = f2b(v);
                else           outf[(size_t)gr * NTOT + gc] = v + bias[gc];
            }
        }
    }
}

// ---------------- e_ns / e_nd from bf16 h: one wave per node, all 4 heads ----------------
__global__ __launch_bounds__(256) void calc_e(const ushort* __restrict__ h,
                                              const float* __restrict__ att_ns,
                                              const float* __restrict__ att_nd,
                                              float* __restrict__ e_ns,
                                              float* __restrict__ e_nd) {
    int n = blockIdx.x * 4 + (threadIdx.x >> 6);
    int lane = threadIdx.x & 63;
    if (n >= N_NODES) return;
    uint4 v = *(const uint4*)&h[(size_t)n * HD + lane * 8];
    float hv[8];
    hv[0] = b2f(v.x & 0xffff); hv[1] = b2f(v.x >> 16);
    hv[2] = b2f(v.y & 0xffff); hv[3] = b2f(v.y >> 16);
    hv[4] = b2f(v.z & 0xffff); hv[5] = b2f(v.z >> 16);
    hv[6] = b2f(v.w & 0xffff); hv[7] = b2f(v.w >> 16);
    float s = 0.f, tt = 0.f;
#pragma unroll
    for (int i = 0; i < 8; ++i) {
        s  += hv[i] * att_ns[lane * 8 + i];
        tt += hv[i] * att_nd[lane * 8 + i];
    }
#pragma unroll
    for (int off = 1; off < 16; off <<= 1) {
        s  += __shfl_xor(s, off);
        tt += __shfl_xor(tt, off);
    }
    if ((lane & 15) == 0) {
        int hh = lane >> 4;
        e_ns[n * NH + hh] = s;
        e_nd[n * NH + hh] = tt;
    }
}

// ---------------- softmax + weighted aggregate: one wave per dst node, bf16 h ----------------
__global__ __launch_bounds__(64) void attn_agg(const ushort* __restrict__ h,
                                               const float* __restrict__ e_ns,
                                               const float* __restrict__ e_nd,
                                               const int* __restrict__ src,
                                               const int* __restrict__ row_st,
                                               const int* __restrict__ edge_l,
                                               ushort* __restrict__ agg) {
    __shared__ float sc[MAXD][NH];
    __shared__ int ssrc[MAXD];
    __shared__ float sinv[NH];
    int n = blockIdx.x;
    int lane = threadIdx.x;
    int beg = row_st[n], end = row_st[n + 1];
    int deg = end - beg;
    if (deg > MAXD) deg = MAXD;  // Poisson(16): never hit

    float4 ed = *(const float4*)&e_nd[n * NH];
    for (int i = lane; i < deg; i += 64) {
        int e = edge_l[beg + i];
        int s = src[e];
        ssrc[i] = s;
        float4 en = *(const float4*)&e_ns[s * NH];
        float4 sv;
        sv.x = en.x + ed.x; sv.x = sv.x > 0.f ? sv.x : 0.2f * sv.x;
        sv.y = en.y + ed.y; sv.y = sv.y > 0.f ? sv.y : 0.2f * sv.y;
        sv.z = en.z + ed.z; sv.z = sv.z > 0.f ? sv.z : 0.2f * sv.z;
        sv.w = en.w + ed.w; sv.w = sv.w > 0.f ? sv.w : 0.2f * sv.w;
        *(float4*)&sc[i][0] = sv;
    }
    __syncthreads();
    if (lane < NH) {
        float m = -1e30f;
        for (int i = 0; i < deg; ++i) m = fmaxf(m, sc[i][lane]);
        float ssum = 0.f;
        for (int i = 0; i < deg; ++i) {
            float ex = __expf(sc[i][lane] - m);
            sc[i][lane] = ex;
            ssum += ex;
        }
        sinv[lane] = deg > 0 ? 1.f / ssum : 0.f;
    }
    __syncthreads();

    int head = lane >> 4;
    float acc[8] = {};
    for (int i = 0; i < deg; ++i) {
        uint4 v = *(const uint4*)&h[(size_t)ssrc[i] * HD + lane * 8];
        float a = sc[i][head];
        acc[0] += a * b2f(v.x & 0xffff); acc[1] += a * b2f(v.x >> 16);
        acc[2] += a * b2f(v.y & 0xffff); acc[3] += a * b2f(v.y >> 16);
        acc[4] += a * b2f(v.z & 0xffff); acc[5] += a * b2f(v.z >> 16);
        acc[6] += a * b2f(v.w & 0xffff); acc[7] += a * b2f(v.w >> 16);
    }
    float wgt = sinv[head];
    uint4 o;
    o.x = (uint)f2b(acc[0] * wgt) | ((uint)f2b(acc[1] * wgt) << 16);
    o.y = (uint)f2b(acc[2] * wgt) | ((uint)f2b(acc[3] * wgt) << 16);
    o.z = (uint)f2b(acc[4] * wgt) | ((uint)f2b(acc[5] * wgt) << 16);
    o.w = (uint)f2b(acc[6] * wgt) | ((uint)f2b(acc[7] * wgt) << 16);
    *(uint4*)&agg[(size_t)n * HD + lane * 8] = o;
}

extern "C" void kernel_launch(void* const* d_in, const int* in_sizes, int n_in,
                              void* d_out, int out_size, void* d_ws, size_t ws_size,
                              hipStream_t stream) {
    const float* feat   = (const float*)d_in[0];
    const float* W_fc   = (const float*)d_in[1];
    const float* att_ns = (const float*)d_in[2];
    const float* att_nd = (const float*)d_in[3];
    const float* W_tr   = (const float*)d_in[4];
    const float* b_tr   = (const float*)d_in[5];
    const int*   src    = (const int*)d_in[6];
    const int*   dst    = (const int*)d_in[7];
    float* out = (float*)d_out;

    char* ws = (char*)d_ws;
    ushort* h     = (ushort*)(ws + 0);           // 10,240,000
    ushort* agg   = (ushort*)(ws + 10240000);    // 10,240,000
    ushort* featb = (ushort*)(ws + 20480000);    // 2,560,000
    ushort* Wfct  = (ushort*)(ws + 23040000);    // 131,072
    ushort* Wtt   = (ushort*)(ws + 23171072);    // 131,072
    float*  e_ns  = (float*)(ws + 23302144);     // 160,000
    float*  e_nd  = (float*)(ws + 23462144);     // 160,000
    int*    deg   = (int*)(ws + 23622144);       // 40,000
    int*    row_st= (int*)(ws + 23662144);       // 40,016
    int*    cursor= (int*)(ws + 23702160);       // 40,000
    int*    edge_l= (int*)(ws + 23742160);       // 640,000 -> total ~24.4 MB

    prep<<<1802, 256, 0, stream>>>(feat, W_fc, W_tr, featb, Wfct, Wtt, deg);
    count_deg<<<(N_EDGES + 255) / 256, 256, 0, stream>>>(dst, deg);
    scan_deg<<<1, 1024, 0, stream>>>(deg, row_st, cursor);
    scatter_edges<<<(N_EDGES + 255) / 256, 256, 0, stream>>>(dst, cursor, edge_l);
    gemm_bf16<DF, HD, 0><<<dim3(HD / 64, (N_NODES + 63) / 64), 256, 0, stream>>>(
        featb, Wfct, nullptr, h, nullptr);
    calc_e<<<(N_NODES + 3) / 4, 256, 0, stream>>>(h, att_ns, att_nd, e_ns, e_nd);
    attn_agg<<<N_NODES, 64, 0, stream>>>(h, e_ns, e_nd, src, row_st, edge_l, agg);
    gemm_bf16<HD, DF, 1><<<dim3(DF / 64, (N_NODES + 63) / 64), 256, 0, stream>>>(
        agg, Wtt, b_tr, nullptr, out);
}

// Round 3
// 90.132 us; speedup vs baseline: 1.9271x; 1.0016x over previous
//
#include <hip/hip_runtime.h>
#include <hip/hip_bf16.h>

#define N_NODES 10000
#define N_EDGES 160000
#define DF 128
#define NH 4
#define HD 512
#define MAXD 256

typedef __attribute__((ext_vector_type(8))) short short8;
typedef __attribute__((ext_vector_type(4))) float f32x4;

__device__ __forceinline__ ushort f2b(float x) {
    union { __hip_bfloat16 b; ushort u; } cv; cv.b = __float2bfloat16(x); return cv.u;
}
__device__ __forceinline__ float bfs(ushort u) { return __uint_as_float(((uint)u) << 16); }
__device__ __forceinline__ float bl(uint v) { return __uint_as_float(v << 16); }
__device__ __forceinline__ float bh(uint v) { return __uint_as_float(v & 0xffff0000u); }

// ---------------- prep: M = blockdiag(W_fc_h @ W_trans_h) [128,512] -> Mt bf16 [c][d];
//                  ep[d][8] = e-projections; zero deg ----------------
__global__ __launch_bounds__(256) void prep(const float* __restrict__ Wfc,
                                            const float* __restrict__ Wt,
                                            const float* __restrict__ att_ns,
                                            const float* __restrict__ att_nd,
                                            ushort* __restrict__ Mt,
                                            float* __restrict__ ep,
                                            int* __restrict__ deg) {
    int b = blockIdx.x;
    int tid = threadIdx.x;
    if (b < 16) {
        // M tile: d in [br*64,+64), c in [bc*64,+64); head = c>>7; K = 128
        __shared__ float As[64][132];   // d x k
        __shared__ float Bs[128][68];   // k x c(local 64)
        int br = b >> 3, bc = b & 7;
        int head = bc >> 1;
        int rowbase = br * 64, colbase = bc * 64;
        int clbase = colbase & 127;
        for (int i = tid; i < 64 * 32; i += 256) {
            int r = i >> 5, c4 = (i & 31) << 2;
            float4 v = *(const float4*)&Wfc[(size_t)(rowbase + r) * HD + head * 128 + c4];
            As[r][c4] = v.x; As[r][c4 + 1] = v.y; As[r][c4 + 2] = v.z; As[r][c4 + 3] = v.w;
        }
        for (int i = tid; i < 128 * 16; i += 256) {
            int r = i >> 4, c4 = (i & 15) << 2;
            float4 v = *(const float4*)&Wt[(size_t)(head * 128 + r) * DF + clbase + c4];
            Bs[r][c4] = v.x; Bs[r][c4 + 1] = v.y; Bs[r][c4 + 2] = v.z; Bs[r][c4 + 3] = v.w;
        }
        __syncthreads();
        int tx = tid & 15, ty = tid >> 4;
        float acc[4][4] = {};
        for (int k = 0; k < 128; ++k) {
            float a[4], bb[4];
#pragma unroll
            for (int i = 0; i < 4; i++) a[i] = As[ty * 4 + i][k];
#pragma unroll
            for (int j = 0; j < 4; j++) bb[j] = Bs[k][tx * 4 + j];
#pragma unroll
            for (int i = 0; i < 4; i++)
#pragma unroll
                for (int j = 0; j < 4; j++) acc[i][j] += a[i] * bb[j];
        }
#pragma unroll
        for (int i = 0; i < 4; i++)
#pragma unroll
            for (int j = 0; j < 4; j++) {
                int c = colbase + tx * 4 + j, d = rowbase + ty * 4 + i;
                Mt[(size_t)c * DF + d] = f2b(acc[i][j]);
            }
    } else if (b == 16) {
        // ep[d*8 + half*4 + h] = sum_k Wfc[d, h*128+k] * att[h,k]
        int d = tid >> 1, half = tid & 1;
        const float* att = half ? att_nd : att_ns;
        float s[4] = {};
        for (int k = 0; k < 128; ++k) {
#pragma unroll
            for (int h = 0; h < 4; ++h)
                s[h] += Wfc[(size_t)d * HD + h * 128 + k] * att[h * 128 + k];
        }
#pragma unroll
        for (int h = 0; h < 4; ++h) ep[d * 8 + half * 4 + h] = s[h];
    } else {
        int i = (b - 17) * 256 + tid;
        if (i < N_NODES) deg[i] = 0;
    }
}

// ---------------- CSR build ----------------
__global__ void count_deg(const int* __restrict__ dst, int* __restrict__ deg) {
    int e = blockIdx.x * blockDim.x + threadIdx.x;
    if (e < N_EDGES) atomicAdd(&deg[dst[e]], 1);
}

__global__ __launch_bounds__(1024) void scan_deg(const int* __restrict__ deg,
                                                 int* __restrict__ row_st,
                                                 int* __restrict__ cursor) {
    __shared__ int wsum[16];
    int t = threadIdx.x;
    int local[10];
    int s = 0;
    if (t < 1000) {
#pragma unroll
        for (int i = 0; i < 10; ++i) { local[i] = deg[t * 10 + i]; s += local[i]; }
    }
    int incl = s;
#pragma unroll
    for (int off = 1; off < 64; off <<= 1) {
        int v = __shfl_up(incl, off);
        if ((t & 63) >= off) incl += v;
    }
    if ((t & 63) == 63) wsum[t >> 6] = incl;
    __syncthreads();
    if (t < 16) {
        int v = wsum[t];
        int inc2 = v;
#pragma unroll
        for (int off = 1; off < 16; off <<= 1) {
            int x = __shfl_up(inc2, off);
            if (t >= off) inc2 += x;
        }
        wsum[t] = inc2 - v;
    }
    __syncthreads();
    if (t < 1000) {
        int run = wsum[t >> 6] + incl - s;
#pragma unroll
        for (int i = 0; i < 10; ++i) {
            row_st[t * 10 + i] = run;
            cursor[t * 10 + i] = run;
            run += local[i];
        }
        if (t == 999) row_st[N_NODES] = run;
    }
}

__global__ void scatter_edges(const int* __restrict__ dst, const int* __restrict__ src,
                              int* __restrict__ cursor, int* __restrict__ edge_s) {
    int e = blockIdx.x * blockDim.x + threadIdx.x;
    if (e < N_EDGES) {
        int p = atomicAdd(&cursor[dst[e]], 1);
        edge_s[p] = src[e];
    }
}

// ---------------- bf16 MFMA GEMM: g[N,512] = feat[N,128] @ M; fused e_ns/e_nd for col-block 0 ----
__device__ __forceinline__ short8 lds_frag(const ushort* __restrict__ S, int row, int chunk) {
    return *(const short8*)&S[(size_t)(row * 16 + (chunk ^ (row & 7))) * 8];
}

__global__ __launch_bounds__(256) void gemm_g(const float* __restrict__ feat,
                                              const ushort* __restrict__ Mt,
                                              const float* __restrict__ ep,
                                              ushort* __restrict__ g,
                                              float* __restrict__ e_ns,
                                              float* __restrict__ e_nd) {
    __shared__ ushort As[64 * 128];
    __shared__ ushort Bs[64 * 128];
    int rowbase = blockIdx.y * 64;
    int colbase = blockIdx.x * 64;
    int t = threadIdx.x, lane = t & 63, w = t >> 6;

    // stage A (feat fp32 -> bf16, swizzled)
    for (int idx = t; idx < 64 * 16; idx += 256) {
        int r = idx >> 4, c = idx & 15;
        int gr = rowbase + r;
        uint4 packed = make_uint4(0, 0, 0, 0);
        if (gr < N_NODES) {
            const float* p = &feat[(size_t)gr * DF + c * 8];
            float4 v0 = *(const float4*)p;
            float4 v1 = *(const float4*)(p + 4);
            packed.x = (uint)f2b(v0.x) | ((uint)f2b(v0.y) << 16);
            packed.y = (uint)f2b(v0.z) | ((uint)f2b(v0.w) << 16);
            packed.z = (uint)f2b(v1.x) | ((uint)f2b(v1.y) << 16);
            packed.w = (uint)f2b(v1.z) | ((uint)f2b(v1.w) << 16);
        }
        *(uint4*)&As[(size_t)(r * 16 + (c ^ (r & 7))) * 8] = packed;
    }
    // stage B (Mt bf16 [c][k])
    for (int idx = t; idx < 64 * 16; idx += 256) {
        int r = idx >> 4, c = idx & 15;
        uint4 v = *(const uint4*)&Mt[(size_t)(colbase + r) * DF + c * 8];
        *(uint4*)&Bs[(size_t)(r * 16 + (c ^ (r & 7))) * 8] = v;
    }
    __syncthreads();

    int wr = (w >> 1) * 32, wc = (w & 1) * 32;
    int lr = lane & 15, hi = lane >> 4;
    f32x4 acc[2][2] = {};
#pragma unroll
    for (int kk = 0; kk < 4; ++kk) {
        int cc = kk * 4 + hi;
        short8 a0 = lds_frag(As, wr + lr, cc);
        short8 a1 = lds_frag(As, wr + 16 + lr, cc);
        short8 b0 = lds_frag(Bs, wc + lr, cc);
        short8 b1 = lds_frag(Bs, wc + 16 + lr, cc);
        acc[0][0] = __builtin_amdgcn_mfma_f32_16x16x32_bf16(a0, b0, acc[0][0], 0, 0, 0);
        acc[0][1] = __builtin_amdgcn_mfma_f32_16x16x32_bf16(a0, b1, acc[0][1], 0, 0, 0);
        acc[1][0] = __builtin_amdgcn_mfma_f32_16x16x32_bf16(a1, b0, acc[1][0], 0, 0, 0);
        acc[1][1] = __builtin_amdgcn_mfma_f32_16x16x32_bf16(a1, b1, acc[1][1], 0, 0, 0);
    }
#pragma unroll
    for (int i = 0; i < 2; ++i)
#pragma unroll
        for (int reg = 0; reg < 4; ++reg) {
            int gr = rowbase + wr + i * 16 + hi * 4 + reg;
            if (gr < N_NODES) {
#pragma unroll
                for (int j = 0; j < 2; ++j) {
                    int gc = colbase + wc + j * 16 + lr;
                    g[(size_t)gr * HD + gc] = f2b(acc[i][j][reg]);
                }
            }
        }

    // fused e_ns/e_nd: only col-block 0 (As tile holds full K=128 of feat)
    if (blockIdx.x == 0) {
        __syncthreads();                 // everyone done reading Bs
        float* eps = (float*)Bs;         // reuse as fp32 [128][8] = 4KB
        for (int i = t; i < 1024; i += 256) eps[i] = ep[i];
        __syncthreads();
        int row = t >> 2, q = t & 3;
        int gr = rowbase + row;
        float s[8] = {};
#pragma unroll
        for (int cc0 = 0; cc0 < 4; ++cc0) {
            int cc = q * 4 + cc0;
            short8 f = lds_frag(As, row, cc);
#pragma unroll
            for (int e = 0; e < 8; ++e) {
                float fv = bfs((ushort)f[e]);
                const float* epd = &eps[(cc * 8 + e) * 8];
#pragma unroll
                for (int o = 0; o < 8; ++o) s[o] += fv * epd[o];
            }
        }
#pragma unroll
        for (int o = 0; o < 8; ++o) {
            s[o] += __shfl_xor(s[o], 1);
            s[o] += __shfl_xor(s[o], 2);
        }
        if (q == 0 && gr < N_NODES) {
            *(float4*)&e_ns[gr * 4] = make_float4(s[0], s[1], s[2], s[3]);
            *(float4*)&e_nd[gr * 4] = make_float4(s[4], s[5], s[6], s[7]);
        }
    }
}

// ---------------- softmax + fused aggregate+project: one wave per dst node, writes out ----------
__global__ __launch_bounds__(64) void attn_agg(const ushort* __restrict__ g,
                                               const float* __restrict__ e_ns,
                                               const float* __restrict__ e_nd,
                                               const int* __restrict__ row_st,
                                               const int* __restrict__ edge_s,
                                               const float* __restrict__ bias,
                                               float* __restrict__ out) {
    __shared__ float sc[MAXD][NH];
    __shared__ int ssrc[MAXD];
    __shared__ float sinv[NH];
    int n = blockIdx.x;
    int lane = threadIdx.x;
    int beg = row_st[n], end = row_st[n + 1];
    int deg = end - beg;
    if (deg > MAXD) deg = MAXD;  // Poisson(16): never hit

    float4 ed = *(const float4*)&e_nd[n * NH];
    for (int i = lane; i < deg; i += 64) {
        int s = edge_s[beg + i];
        ssrc[i] = s;
        float4 en = *(const float4*)&e_ns[s * NH];
        float4 sv;
        sv.x = en.x + ed.x; sv.x = sv.x > 0.f ? sv.x : 0.2f * sv.x;
        sv.y = en.y + ed.y; sv.y = sv.y > 0.f ? sv.y : 0.2f * sv.y;
        sv.z = en.z + ed.z; sv.z = sv.z > 0.f ? sv.z : 0.2f * sv.z;
        sv.w = en.w + ed.w; sv.w = sv.w > 0.f ? sv.w : 0.2f * sv.w;
        *(float4*)&sc[i][0] = sv;
    }
    __syncthreads();
    // parallel softmax: 16 lanes per head
    {
        int h = lane >> 4, il = lane & 15;
        float m = -1e30f;
        for (int i = il; i < deg; i += 16) m = fmaxf(m, sc[i][h]);
#pragma unroll
        for (int off = 8; off > 0; off >>= 1) m = fmaxf(m, __shfl_xor(m, off));
        float ssum = 0.f;
        for (int i = il; i < deg; i += 16) {
            float ex = __expf(sc[i][h] - m);
            sc[i][h] = ex;
            ssum += ex;
        }
#pragma unroll
        for (int off = 8; off > 0; off >>= 1) ssum += __shfl_xor(ssum, off);
        if (il == 0) sinv[h] = deg > 0 ? 1.f / ssum : 0.f;
    }
    __syncthreads();

    // gather g rows (4 heads x 2 cols per lane), accumulate per head
    int c2 = lane * 2;
    float acc[NH][2] = {};
    for (int i = 0; i < deg; ++i) {
        const ushort* gp = g + (size_t)ssrc[i] * HD;
        float a0 = sc[i][0], a1 = sc[i][1], a2 = sc[i][2], a3 = sc[i][3];
        uint v0 = *(const uint*)&gp[c2];
        uint v1 = *(const uint*)&gp[128 + c2];
        uint v2 = *(const uint*)&gp[256 + c2];
        uint v3 = *(const uint*)&gp[384 + c2];
        acc[0][0] += a0 * bl(v0); acc[0][1] += a0 * bh(v0);
        acc[1][0] += a1 * bl(v1); acc[1][1] += a1 * bh(v1);
        acc[2][0] += a2 * bl(v2); acc[2][1] += a2 * bh(v2);
        acc[3][0] += a3 * bl(v3); acc[3][1] += a3 * bh(v3);
    }
    float w0 = sinv[0], w1 = sinv[1], w2 = sinv[2], w3 = sinv[3];
    float o0 = acc[0][0] * w0 + acc[1][0] * w1 + acc[2][0] * w2 + acc[3][0] * w3 + bias[c2];
    float o1 = acc[0][1] * w0 + acc[1][1] * w1 + acc[2][1] * w2 + acc[3][1] * w3 + bias[c2 + 1];
    *(float2*)&out[(size_t)n * DF + c2] = make_float2(o0, o1);
}

extern "C" void kernel_launch(void* const* d_in, const int* in_sizes, int n_in,
                              void* d_out, int out_size, void* d_ws, size_t ws_size,
                              hipStream_t stream) {
    const float* feat   = (const float*)d_in[0];
    const float* W_fc   = (const float*)d_in[1];
    const float* att_ns = (const float*)d_in[2];
    const float* att_nd = (const float*)d_in[3];
    const float* W_tr   = (const float*)d_in[4];
    const float* b_tr   = (const float*)d_in[5];
    const int*   src    = (const int*)d_in[6];
    const int*   dst    = (const int*)d_in[7];
    float* out = (float*)d_out;

    char* ws = (char*)d_ws;
    ushort* g      = (ushort*)(ws + 0);          // 10,240,000
    ushort* Mt     = (ushort*)(ws + 10240000);   //    131,072
    float*  ep     = (float*)(ws + 10371072);    //      4,096
    float*  e_ns   = (float*)(ws + 10375168);    //    160,000
    float*  e_nd   = (float*)(ws + 10535168);    //    160,000
    int*    deg    = (int*)(ws + 10695168);      //     40,000
    int*    row_st = (int*)(ws + 10735168);      //     40,016
    int*    cursor = (int*)(ws + 10775184);      //     40,000
    int*    edge_s = (int*)(ws + 10815184);      //    640,000  -> ~11.5 MB

    prep<<<57, 256, 0, stream>>>(W_fc, W_tr, att_ns, att_nd, Mt, ep, deg);
    count_deg<<<(N_EDGES + 255) / 256, 256, 0, stream>>>(dst, deg);
    scan_deg<<<1, 1024, 0, stream>>>(deg, row_st, cursor);
    scatter_edges<<<(N_EDGES + 255) / 256, 256, 0, stream>>>(dst, src, cursor, edge_s);
    gemm_g<<<dim3(HD / 64, (N_NODES + 63) / 64), 256, 0, stream>>>(feat, Mt, ep, g, e_ns, e_nd);
    attn_agg<<<N_NODES, 64, 0, stream>>>(g, e_ns, e_nd, row_st, edge_s, b_tr, out);
}

// Round 4
// 80.771 us; speedup vs baseline: 2.1505x; 1.1159x over previous
//
#include <hip/hip_runtime.h>
#include <hip/hip_bf16.h>

#define N_NODES 10000
#define N_EDGES 160000
#define DF 128
#define NH 4
#define HD 512
#define MAXD 256

typedef __attribute__((ext_vector_type(8))) short short8;
typedef __attribute__((ext_vector_type(4))) float f32x4;

__device__ __forceinline__ ushort f2b(float x) {
    union { __hip_bfloat16 b; ushort u; } cv; cv.b = __float2bfloat16(x); return cv.u;
}
__device__ __forceinline__ float bfs(ushort u) { return __uint_as_float(((uint)u) << 16); }
__device__ __forceinline__ float bl(uint v) { return __uint_as_float(v << 16); }
__device__ __forceinline__ float bh(uint v) { return __uint_as_float(v & 0xffff0000u); }

// ---------------- prep: 16 blocks M-tiles; 8 blocks ep; 40 blocks zero deg ----------------
__global__ __launch_bounds__(256) void prep(const float* __restrict__ Wfc,
                                            const float* __restrict__ Wt,
                                            const float* __restrict__ att_ns,
                                            const float* __restrict__ att_nd,
                                            ushort* __restrict__ Mt,
                                            float* __restrict__ ep,
                                            int* __restrict__ deg) {
    int b = blockIdx.x;
    int tid = threadIdx.x;
    if (b < 16) {
        // M = blockdiag(Wfc_h @ Wt_h): tile d in [br*64,+64), c in [bc*64,+64), K=128 (fp32)
        __shared__ float As[64][132];
        __shared__ float Bs[128][68];
        int br = b >> 3, bc = b & 7;
        int head = bc >> 1;
        int rowbase = br * 64, colbase = bc * 64;
        int clbase = colbase & 127;
        for (int i = tid; i < 64 * 32; i += 256) {
            int r = i >> 5, c4 = (i & 31) << 2;
            float4 v = *(const float4*)&Wfc[(size_t)(rowbase + r) * HD + head * 128 + c4];
            As[r][c4] = v.x; As[r][c4 + 1] = v.y; As[r][c4 + 2] = v.z; As[r][c4 + 3] = v.w;
        }
        for (int i = tid; i < 128 * 16; i += 256) {
            int r = i >> 4, c4 = (i & 15) << 2;
            float4 v = *(const float4*)&Wt[(size_t)(head * 128 + r) * DF + clbase + c4];
            Bs[r][c4] = v.x; Bs[r][c4 + 1] = v.y; Bs[r][c4 + 2] = v.z; Bs[r][c4 + 3] = v.w;
        }
        __syncthreads();
        int tx = tid & 15, ty = tid >> 4;
        float acc[4][4] = {};
        for (int k = 0; k < 128; ++k) {
            float a[4], bb[4];
#pragma unroll
            for (int i = 0; i < 4; i++) a[i] = As[ty * 4 + i][k];
#pragma unroll
            for (int j = 0; j < 4; j++) bb[j] = Bs[k][tx * 4 + j];
#pragma unroll
            for (int i = 0; i < 4; i++)
#pragma unroll
                for (int j = 0; j < 4; j++) acc[i][j] += a[i] * bb[j];
        }
#pragma unroll
        for (int i = 0; i < 4; i++)
#pragma unroll
            for (int j = 0; j < 4; j++) {
                int c = colbase + tx * 4 + j, d = rowbase + ty * 4 + i;
                Mt[(size_t)c * DF + d] = f2b(acc[i][j]);
            }
    } else if (b < 24) {
        // ep[d*8 + half*4 + h] = sum_k Wfc[d, h*128+k] * att[h,k];  2 threads per output
        int bb = b - 16;
        int oidx = tid >> 1, kh = tid & 1;
        int dl = oidx >> 3, half = (oidx >> 2) & 1, h = oidx & 3;
        int d = bb * 16 + dl;
        const float* att = half ? att_nd : att_ns;
        float s = 0.f;
        int k0 = kh * 64;
        for (int k = k0; k < k0 + 64; ++k)
            s += Wfc[(size_t)d * HD + h * 128 + k] * att[h * 128 + k];
        s += __shfl_xor(s, 1);
        if (kh == 0) ep[d * 8 + half * 4 + h] = s;
    } else {
        int i = (b - 24) * 256 + tid;
        if (i < N_NODES) deg[i] = 0;
    }
}

// ---------------- CSR build ----------------
__global__ void count_deg(const int* __restrict__ dst, int* __restrict__ deg) {
    int e = blockIdx.x * blockDim.x + threadIdx.x;
    if (e < N_EDGES) atomicAdd(&deg[dst[e]], 1);
}

__global__ __launch_bounds__(1024) void scan_deg(const int* __restrict__ deg,
                                                 int* __restrict__ row_st,
                                                 int* __restrict__ cursor) {
    __shared__ int wsum[16];
    int t = threadIdx.x;
    int local[10];
    int s = 0;
    if (t < 1000) {
#pragma unroll
        for (int i = 0; i < 10; ++i) { local[i] = deg[t * 10 + i]; s += local[i]; }
    }
    int incl = s;
#pragma unroll
    for (int off = 1; off < 64; off <<= 1) {
        int v = __shfl_up(incl, off);
        if ((t & 63) >= off) incl += v;
    }
    if ((t & 63) == 63) wsum[t >> 6] = incl;
    __syncthreads();
    if (t < 16) {
        int v = wsum[t];
        int inc2 = v;
#pragma unroll
        for (int off = 1; off < 16; off <<= 1) {
            int x = __shfl_up(inc2, off);
            if (t >= off) inc2 += x;
        }
        wsum[t] = inc2 - v;
    }
    __syncthreads();
    if (t < 1000) {
        int run = wsum[t >> 6] + incl - s;
#pragma unroll
        for (int i = 0; i < 10; ++i) {
            row_st[t * 10 + i] = run;
            cursor[t * 10 + i] = run;
            run += local[i];
        }
        if (t == 999) row_st[N_NODES] = run;
    }
}

// scatter edges into CSR order; precompute LeakyReLU scores per edge
__global__ void scatter_edges(const int* __restrict__ dst, const int* __restrict__ src,
                              const float* __restrict__ e_ns, const float* __restrict__ e_nd,
                              int* __restrict__ cursor, int* __restrict__ edge_s,
                              float* __restrict__ escore) {
    int e = blockIdx.x * blockDim.x + threadIdx.x;
    if (e < N_EDGES) {
        int d = dst[e], s = src[e];
        float4 en = *(const float4*)&e_ns[s * 4];
        float4 ed = *(const float4*)&e_nd[d * 4];
        float4 sv;
        sv.x = en.x + ed.x; sv.x = sv.x > 0.f ? sv.x : 0.2f * sv.x;
        sv.y = en.y + ed.y; sv.y = sv.y > 0.f ? sv.y : 0.2f * sv.y;
        sv.z = en.z + ed.z; sv.z = sv.z > 0.f ? sv.z : 0.2f * sv.z;
        sv.w = en.w + ed.w; sv.w = sv.w > 0.f ? sv.w : 0.2f * sv.w;
        int p = atomicAdd(&cursor[d], 1);
        edge_s[p] = s;
        *(float4*)&escore[(size_t)p * 4] = sv;
    }
}

// ---------------- bf16 MFMA GEMM: g = feat @ M, BM=64 BN=256 (4 col-tiles); fused e ----------
__device__ __forceinline__ short8 lds_frag(const ushort* __restrict__ S, int row, int chunk) {
    return *(const short8*)&S[(size_t)(row * 16 + (chunk ^ (row & 7))) * 8];
}

__global__ __launch_bounds__(256) void gemm_g(const float* __restrict__ feat,
                                              const ushort* __restrict__ Mt,
                                              const float* __restrict__ ep,
                                              ushort* __restrict__ g,
                                              float* __restrict__ e_ns,
                                              float* __restrict__ e_nd) {
    __shared__ ushort As[64 * 128];
    __shared__ ushort Bs[64 * 128];
    int rowbase = blockIdx.y * 64;
    int colhalf = blockIdx.x;   // 0..1
    int t = threadIdx.x, lane = t & 63, w = t >> 6;

    // stage A once (feat fp32 -> bf16, swizzled)
    for (int idx = t; idx < 64 * 16; idx += 256) {
        int r = idx >> 4, c = idx & 15;
        int gr = rowbase + r;
        uint4 packed = make_uint4(0, 0, 0, 0);
        if (gr < N_NODES) {
            const float* p = &feat[(size_t)gr * DF + c * 8];
            float4 v0 = *(const float4*)p;
            float4 v1 = *(const float4*)(p + 4);
            packed.x = (uint)f2b(v0.x) | ((uint)f2b(v0.y) << 16);
            packed.y = (uint)f2b(v0.z) | ((uint)f2b(v0.w) << 16);
            packed.z = (uint)f2b(v1.x) | ((uint)f2b(v1.y) << 16);
            packed.w = (uint)f2b(v1.z) | ((uint)f2b(v1.w) << 16);
        }
        *(uint4*)&As[(size_t)(r * 16 + (c ^ (r & 7))) * 8] = packed;
    }

    int wr = (w >> 1) * 32, wc = (w & 1) * 32;
    int lr = lane & 15, hi = lane >> 4;

    for (int ct = 0; ct < 4; ++ct) {
        int colbase = colhalf * 256 + ct * 64;
        // stage B tile (Mt bf16 [c][k])
        for (int idx = t; idx < 64 * 16; idx += 256) {
            int r = idx >> 4, c = idx & 15;
            uint4 v = *(const uint4*)&Mt[(size_t)(colbase + r) * DF + c * 8];
            *(uint4*)&Bs[(size_t)(r * 16 + (c ^ (r & 7))) * 8] = v;
        }
        __syncthreads();
        f32x4 acc[2][2] = {};
#pragma unroll
        for (int kk = 0; kk < 4; ++kk) {
            int cc = kk * 4 + hi;
            short8 a0 = lds_frag(As, wr + lr, cc);
            short8 a1 = lds_frag(As, wr + 16 + lr, cc);
            short8 b0 = lds_frag(Bs, wc + lr, cc);
            short8 b1 = lds_frag(Bs, wc + 16 + lr, cc);
            acc[0][0] = __builtin_amdgcn_mfma_f32_16x16x32_bf16(a0, b0, acc[0][0], 0, 0, 0);
            acc[0][1] = __builtin_amdgcn_mfma_f32_16x16x32_bf16(a0, b1, acc[0][1], 0, 0, 0);
            acc[1][0] = __builtin_amdgcn_mfma_f32_16x16x32_bf16(a1, b0, acc[1][0], 0, 0, 0);
            acc[1][1] = __builtin_amdgcn_mfma_f32_16x16x32_bf16(a1, b1, acc[1][1], 0, 0, 0);
        }
#pragma unroll
        for (int i = 0; i < 2; ++i)
#pragma unroll
            for (int reg = 0; reg < 4; ++reg) {
                int gr = rowbase + wr + i * 16 + hi * 4 + reg;
                if (gr < N_NODES) {
#pragma unroll
                    for (int j = 0; j < 2; ++j) {
                        int gc = colbase + wc + j * 16 + lr;
                        g[(size_t)gr * HD + gc] = f2b(acc[i][j][reg]);
                    }
                }
            }
        __syncthreads();
    }

    // fused e_ns/e_nd (colhalf 0 only): As holds full K=128 of feat for these rows
    if (colhalf == 0) {
        float* eps = (float*)Bs;  // fp32 [128][8] = 4KB
        for (int i = t; i < 1024; i += 256) eps[i] = ep[i];
        __syncthreads();
        int row = t >> 2, q = t & 3;
        int gr = rowbase + row;
        float s[8] = {};
#pragma unroll
        for (int cc0 = 0; cc0 < 4; ++cc0) {
            int cc = q * 4 + cc0;
            short8 f = lds_frag(As, row, cc);
#pragma unroll
            for (int e = 0; e < 8; ++e) {
                float fv = bfs((ushort)f[e]);
                const float* epd = &eps[(cc * 8 + e) * 8];
#pragma unroll
                for (int o = 0; o < 8; ++o) s[o] += fv * epd[o];
            }
        }
#pragma unroll
        for (int o = 0; o < 8; ++o) {
            s[o] += __shfl_xor(s[o], 1);
            s[o] += __shfl_xor(s[o], 2);
        }
        if (q == 0 && gr < N_NODES) {
            *(float4*)&e_ns[gr * 4] = make_float4(s[0], s[1], s[2], s[3]);
            *(float4*)&e_nd[gr * 4] = make_float4(s[4], s[5], s[6], s[7]);
        }
    }
}

// ---------------- softmax + fused aggregate+project: one wave per dst node ----------------
__global__ __launch_bounds__(64) void attn_agg(const ushort* __restrict__ g,
                                               const int* __restrict__ row_st,
                                               const int* __restrict__ edge_s,
                                               const float* __restrict__ escore,
                                               const float* __restrict__ bias,
                                               float* __restrict__ out) {
    __shared__ float sc[MAXD][NH];
    __shared__ int ssrc[MAXD];
    __shared__ float sinv[NH];
    int n = blockIdx.x;
    int lane = threadIdx.x;
    int beg = row_st[n], end = row_st[n + 1];
    int deg = end - beg;
    if (deg > MAXD) deg = MAXD;  // Poisson(16): never hit

    for (int i = lane; i < deg; i += 64) {
        ssrc[i] = edge_s[beg + i];
        *(float4*)&sc[i][0] = *(const float4*)&escore[(size_t)(beg + i) * 4];
    }
    __syncthreads();
    // parallel softmax: 16 lanes per head
    {
        int h = lane >> 4, il = lane & 15;
        float m = -1e30f;
        for (int i = il; i < deg; i += 16) m = fmaxf(m, sc[i][h]);
#pragma unroll
        for (int off = 8; off > 0; off >>= 1) m = fmaxf(m, __shfl_xor(m, off));
        float ssum = 0.f;
        for (int i = il; i < deg; i += 16) {
            float ex = __expf(sc[i][h] - m);
            sc[i][h] = ex;
            ssum += ex;
        }
#pragma unroll
        for (int off = 8; off > 0; off >>= 1) ssum += __shfl_xor(ssum, off);
        if (il == 0) sinv[h] = deg > 0 ? 1.f / ssum : 0.f;
    }
    __syncthreads();

    int c2 = lane * 2;
    float acc[NH][2] = {};
    for (int i = 0; i < deg; ++i) {
        const ushort* gp = g + (size_t)ssrc[i] * HD;
        float a0 = sc[i][0], a1 = sc[i][1], a2 = sc[i][2], a3 = sc[i][3];
        uint v0 = *(const uint*)&gp[c2];
        uint v1 = *(const uint*)&gp[128 + c2];
        uint v2 = *(const uint*)&gp[256 + c2];
        uint v3 = *(const uint*)&gp[384 + c2];
        acc[0][0] += a0 * bl(v0); acc[0][1] += a0 * bh(v0);
        acc[1][0] += a1 * bl(v1); acc[1][1] += a1 * bh(v1);
        acc[2][0] += a2 * bl(v2); acc[2][1] += a2 * bh(v2);
        acc[3][0] += a3 * bl(v3); acc[3][1] += a3 * bh(v3);
    }
    float w0 = sinv[0], w1 = sinv[1], w2 = sinv[2], w3 = sinv[3];
    float o0 = acc[0][0] * w0 + acc[1][0] * w1 + acc[2][0] * w2 + acc[3][0] * w3 + bias[c2];
    float o1 = acc[0][1] * w0 + acc[1][1] * w1 + acc[2][1] * w2 + acc[3][1] * w3 + bias[c2 + 1];
    *(float2*)&out[(size_t)n * DF + c2] = make_float2(o0, o1);
}

extern "C" void kernel_launch(void* const* d_in, const int* in_sizes, int n_in,
                              void* d_out, int out_size, void* d_ws, size_t ws_size,
                              hipStream_t stream) {
    const float* feat   = (const float*)d_in[0];
    const float* W_fc   = (const float*)d_in[1];
    const float* att_ns = (const float*)d_in[2];
    const float* att_nd = (const float*)d_in[3];
    const float* W_tr   = (const float*)d_in[4];
    const float* b_tr   = (const float*)d_in[5];
    const int*   src    = (const int*)d_in[6];
    const int*   dst    = (const int*)d_in[7];
    float* out = (float*)d_out;

    char* ws = (char*)d_ws;
    ushort* g      = (ushort*)(ws + 0);          // 10,240,000
    ushort* Mt     = (ushort*)(ws + 10240000);   //    131,072
    float*  ep     = (float*)(ws + 10371072);    //      4,096
    float*  e_ns   = (float*)(ws + 10375168);    //    160,000
    float*  e_nd   = (float*)(ws + 10535168);    //    160,000
    float*  escore = (float*)(ws + 10695168);    //  2,560,000
    int*    deg    = (int*)(ws + 13255168);      //     40,000
    int*    row_st = (int*)(ws + 13295168);      //     40,016
    int*    cursor = (int*)(ws + 13335184);      //     40,000
    int*    edge_s = (int*)(ws + 13375184);      //    640,000  -> ~14 MB

    prep<<<64, 256, 0, stream>>>(W_fc, W_tr, att_ns, att_nd, Mt, ep, deg);
    count_deg<<<(N_EDGES + 255) / 256, 256, 0, stream>>>(dst, deg);
    scan_deg<<<1, 1024, 0, stream>>>(deg, row_st, cursor);
    gemm_g<<<dim3(2, (N_NODES + 63) / 64), 256, 0, stream>>>(feat, Mt, ep, g, e_ns, e_nd);
    scatter_edges<<<(N_EDGES + 255) / 256, 256, 0, stream>>>(dst, src, e_ns, e_nd,
                                                             cursor, edge_s, escore);
    attn_agg<<<N_NODES, 64, 0, stream>>>(g, row_st, edge_s, escore, b_tr, out);
}